// Round 1
// baseline (176.643 us; speedup 1.0000x reference)
//
#include <hip/hip_runtime.h>
#include <math.h>

// Reduction layout (21 accumulators):
//   [0..5]   Sx[c]   = sum output[:,c]
//   [6..11]  Sxx[c]  = sum output[:,c]^2
//   [12..17] Sxy[c]  = sum output[:,c]*label
//   [18]     Sy      = sum label
//   [19]     Syy     = sum label^2
//   [20]     Hsum    = sum_rows sum_c huber*alpha
static constexpr int BLOCK = 256;
static constexpr int NACC  = 21;

__device__ __forceinline__ float fast_tanh_sq(float d) {
    // tanh(d) = 1 - 2/(exp(2d)+1); squared. exp via fast native path.
    float e = __expf(2.0f * d);
    float r = __builtin_amdgcn_rcpf(e + 1.0f);
    float t = 1.0f - 2.0f * r;
    return t * t;
}

__device__ __forceinline__ void row_accum(float acc[NACC], const float x[6], float y) {
    acc[18] += y;
    acc[19] += y * y;
    float rowh = 0.0f;
#pragma unroll
    for (int c = 0; c < 6; ++c) {
        const float xv = x[c];
        acc[c]      += xv;
        acc[6 + c]  += xv * xv;
        acc[12 + c] += xv * y;
        const float d   = xv - y;
        const float hub = 4.0f * (__builtin_amdgcn_sqrtf(1.0f + 0.25f * d * d) - 1.0f);
        const float al  = (c < 5) ? (0.2f * fast_tanh_sq(d)) : 1.0f;
        rowh += hub * al;
    }
    acc[20] += rowh;
}

__global__ __launch_bounds__(BLOCK) void huber_partial_kernel(
    const float* __restrict__ out6,
    const float* __restrict__ lab,
    float* __restrict__ part,
    int n)
{
    float acc[NACC];
#pragma unroll
    for (int k = 0; k < NACC; ++k) acc[k] = 0.0f;

    const int npairs = n >> 1;
    const int tid    = blockIdx.x * blockDim.x + threadIdx.x;
    const int stride = gridDim.x * blockDim.x;

    // Each iteration handles 2 rows = 48B of `output` (three aligned float4)
    // plus 2 labels (one float2).
    for (int p = tid; p < npairs; p += stride) {
        const float4* base = reinterpret_cast<const float4*>(out6 + (size_t)p * 12);
        const float4 a = base[0];
        const float4 b = base[1];
        const float4 c = base[2];
        const float2 y2 = *reinterpret_cast<const float2*>(lab + (size_t)p * 2);

        const float r0[6] = {a.x, a.y, a.z, a.w, b.x, b.y};
        const float r1[6] = {b.z, b.w, c.x, c.y, c.z, c.w};
        row_accum(acc, r0, y2.x);
        row_accum(acc, r1, y2.y);
    }

    // Odd tail row (n odd): one thread handles it scalar.
    if ((n & 1) && tid == 0) {
        const size_t row = (size_t)n - 1;
        float xr[6];
#pragma unroll
        for (int c = 0; c < 6; ++c) xr[c] = out6[row * 6 + c];
        row_accum(acc, xr, lab[row]);
    }

    // Wave (64-lane) shuffle reduction for each of the 21 accumulators.
#pragma unroll
    for (int k = 0; k < NACC; ++k) {
        float v = acc[k];
#pragma unroll
        for (int off = 32; off > 0; off >>= 1)
            v += __shfl_down(v, off, 64);
        acc[k] = v;
    }

    __shared__ float red[BLOCK / 64][NACC];
    const int wave = threadIdx.x >> 6;
    const int lane = threadIdx.x & 63;
    if (lane == 0) {
#pragma unroll
        for (int k = 0; k < NACC; ++k) red[wave][k] = acc[k];
    }
    __syncthreads();
    if (threadIdx.x < NACC) {
        float s = 0.0f;
#pragma unroll
        for (int w = 0; w < BLOCK / 64; ++w) s += red[w][threadIdx.x];
        part[(size_t)blockIdx.x * NACC + threadIdx.x] = s;
    }
}

__global__ __launch_bounds__(64) void huber_final_kernel(
    const float* __restrict__ part, int nblocks, int n, float* __restrict__ out)
{
    double acc[NACC];
#pragma unroll
    for (int k = 0; k < NACC; ++k) acc[k] = 0.0;

    for (int b = threadIdx.x; b < nblocks; b += 64) {
        const float* p = part + (size_t)b * NACC;
#pragma unroll
        for (int k = 0; k < NACC; ++k) acc[k] += (double)p[k];
    }

#pragma unroll
    for (int k = 0; k < NACC; ++k) {
        double v = acc[k];
#pragma unroll
        for (int off = 32; off > 0; off >>= 1)
            v += __shfl_down(v, off, 64);
        acc[k] = v;
    }

    if (threadIdx.x == 0) {
        const double dn  = (double)n;
        const double Sy  = acc[18];
        const double Syy = acc[19];
        const double vary = Syy - Sy * Sy / dn;
        double pc[6];
#pragma unroll
        for (int c = 0; c < 6; ++c) {
            const double Sx  = acc[c];
            const double Sxx = acc[6 + c];
            const double Sxy = acc[12 + c];
            const double cov  = Sxy - Sx * Sy / dn;
            const double varx = Sxx - Sx * Sx / dn;
            pc[c] = cov / (sqrt(varx) * sqrt(vary));
        }
        const double loss_old = acc[20] / dn;
        const double s = 5.0 - pc[0] - pc[1] - pc[2] - pc[3] - pc[4];
        double pen = 0.0;
#pragma unroll
        for (int c = 0; c < 5; ++c) pen += (1.0 - pc[c]) * (1.0 - pc[c]);
        pen /= s;
        const double loss = loss_old + pen + (1.0 - pc[5]);
        out[0] = (float)loss;
    }
}

extern "C" void kernel_launch(void* const* d_in, const int* in_sizes, int n_in,
                              void* d_out, int out_size, void* d_ws, size_t ws_size,
                              hipStream_t stream) {
    const float* out6 = (const float*)d_in[0];  // (n,6) f32 row-major
    const float* lab  = (const float*)d_in[1];  // (n,1) f32
    float* out = (float*)d_out;
    const int n = in_sizes[1];

    int nblocks = 2048;  // grid-stride cap (G11)
    const int maxb = (int)(ws_size / (NACC * sizeof(float)));
    if (nblocks > maxb) nblocks = maxb;
    int npairs = n >> 1;
    if (npairs < 1) npairs = 1;
    const int needed = (npairs + BLOCK - 1) / BLOCK;
    if (nblocks > needed) nblocks = needed;
    if (nblocks < 1) nblocks = 1;

    float* part = (float*)d_ws;
    hipLaunchKernelGGL(huber_partial_kernel, dim3(nblocks), dim3(BLOCK), 0, stream,
                       out6, lab, part, n);
    hipLaunchKernelGGL(huber_final_kernel, dim3(1), dim3(64), 0, stream,
                       part, nblocks, n, out);
}

// Round 2
// 165.526 us; speedup vs baseline: 1.0672x; 1.0672x over previous
//
#include <hip/hip_runtime.h>
#include <math.h>

// Reduction layout (21 accumulators, stored padded to stride 24):
//   [0..5]   Sx[c]   = sum output[:,c]
//   [6..11]  Sxx[c]  = sum output[:,c]^2
//   [12..17] Sxy[c]  = sum output[:,c]*label
//   [18]     Sy      = sum label
//   [19]     Syy     = sum label^2
//   [20]     Hsum    = sum_rows sum_c huber*alpha
static constexpr int BLOCK     = 256;
static constexpr int NACC      = 21;
static constexpr int PSTRIDE   = 24;   // padded partial stride (float4-friendly)
static constexpr int TILE_ROWS = 512;                 // rows per LDS tile
static constexpr int TILE_F4   = TILE_ROWS * 6 / 4;   // 768 float4 = 12 KB
static constexpr int MAXBLOCKS = 2048;

__device__ __forceinline__ float fast_tanh_sq(float d) {
    // tanh(d) = 1 - 2/(exp(2d)+1); squared.
    float e = __expf(2.0f * d);
    float r = __builtin_amdgcn_rcpf(e + 1.0f);
    float t = 1.0f - 2.0f * r;
    return t * t;
}

__device__ __forceinline__ void row_accum(float acc[NACC], const float x[6], float y) {
    acc[18] += y;
    acc[19] += y * y;
    float rowh = 0.0f;
#pragma unroll
    for (int c = 0; c < 6; ++c) {
        const float xv = x[c];
        acc[c]      += xv;
        acc[6 + c]  += xv * xv;
        acc[12 + c] += xv * y;
        const float d   = xv - y;
        const float hub = 4.0f * (__builtin_amdgcn_sqrtf(1.0f + 0.25f * d * d) - 1.0f);
        const float al  = (c < 5) ? (0.2f * fast_tanh_sq(d)) : 1.0f;
        rowh += hub * al;
    }
    acc[20] += rowh;
}

__global__ __launch_bounds__(BLOCK) void huber_partial_kernel(
    const float* __restrict__ out6,
    const float* __restrict__ lab,
    float* __restrict__ part,
    int n)
{
    __shared__ float4 tile[TILE_F4];          // 12 KB
    __shared__ float  red[BLOCK / 64][NACC];  // cross-wave reduce

    float acc[NACC];
#pragma unroll
    for (int k = 0; k < NACC; ++k) acc[k] = 0.0f;

    const int t  = threadIdx.x;
    const int n2 = n & ~1;                      // even-row body; odd tail handled below
    const long long nf4 = ((long long)n2 * 6) >> 2;
    const int ntiles = (n2 + TILE_ROWS - 1) / TILE_ROWS;
    const float4* gsrc = reinterpret_cast<const float4*>(out6);

    for (int tl = blockIdx.x; tl < ntiles; tl += gridDim.x) {
        const long long basef4 = (long long)tl * TILE_F4;

        // Global -> LDS, perfectly coalesced (lane stride 16 B).
#pragma unroll
        for (int k = 0; k < 3; ++k) {
            const long long g = basef4 + k * BLOCK + t;
            float4 v = make_float4(0.f, 0.f, 0.f, 0.f);
            if (g < nf4) v = gsrc[g];
            tile[k * BLOCK + t] = v;
        }

        // Labels for this thread's two rows: aligned float2, lane stride 8 B.
        const int r0 = tl * TILE_ROWS + 2 * t;
        float2 y2 = make_float2(0.f, 0.f);
        if (r0 + 1 < n2)
            y2 = *reinterpret_cast<const float2*>(lab + r0);
        __syncthreads();

        if (r0 + 1 < n2) {
            // LDS -> 2 rows (48 B contiguous per thread; (3t+k)&7 covers all
            // 8 bank groups uniformly -> conflict-free).
            const float4 a = tile[3 * t + 0];
            const float4 b = tile[3 * t + 1];
            const float4 c = tile[3 * t + 2];
            const float r0v[6] = {a.x, a.y, a.z, a.w, b.x, b.y};
            const float r1v[6] = {b.z, b.w, c.x, c.y, c.z, c.w};
            row_accum(acc, r0v, y2.x);
            row_accum(acc, r1v, y2.y);
        }
        __syncthreads();  // protect tile before next iteration's writes
    }

    // Odd tail row (n odd): one thread, scalar.
    if ((n & 1) && blockIdx.x == 0 && t == 0) {
        const size_t row = (size_t)n - 1;
        float xr[6];
#pragma unroll
        for (int c = 0; c < 6; ++c) xr[c] = out6[row * 6 + c];
        row_accum(acc, xr, lab[row]);
    }

    // Wave (64-lane) shuffle reduction.
#pragma unroll
    for (int k = 0; k < NACC; ++k) {
        float v = acc[k];
#pragma unroll
        for (int off = 32; off > 0; off >>= 1)
            v += __shfl_down(v, off, 64);
        acc[k] = v;
    }

    const int wave = t >> 6;
    const int lane = t & 63;
    if (lane == 0) {
#pragma unroll
        for (int k = 0; k < NACC; ++k) red[wave][k] = acc[k];
    }
    __syncthreads();
    if (t < NACC) {
        float s = 0.0f;
#pragma unroll
        for (int w = 0; w < BLOCK / 64; ++w) s += red[w][t];
        part[(size_t)blockIdx.x * PSTRIDE + t] = s;
    }
}

__global__ __launch_bounds__(BLOCK) void huber_final_kernel(
    const float* __restrict__ part, int nblocks, int n, float* __restrict__ out)
{
    __shared__ double sred[BLOCK / 64][NACC];

    double acc[NACC];
#pragma unroll
    for (int k = 0; k < NACC; ++k) acc[k] = 0.0;

    // Padded stride-24 partials: 5x float4 + 1 scalar per block record.
    for (int b = threadIdx.x; b < nblocks; b += BLOCK) {
        const float* p = part + (size_t)b * PSTRIDE;
        const float4* p4 = reinterpret_cast<const float4*>(p);
#pragma unroll
        for (int q = 0; q < 5; ++q) {
            const float4 v = p4[q];
            acc[q * 4 + 0] += (double)v.x;
            acc[q * 4 + 1] += (double)v.y;
            acc[q * 4 + 2] += (double)v.z;
            acc[q * 4 + 3] += (double)v.w;
        }
        acc[20] += (double)p[20];
    }

#pragma unroll
    for (int k = 0; k < NACC; ++k) {
        double v = acc[k];
#pragma unroll
        for (int off = 32; off > 0; off >>= 1)
            v += __shfl_down(v, off, 64);
        acc[k] = v;
    }

    const int wave = threadIdx.x >> 6;
    const int lane = threadIdx.x & 63;
    if (lane == 0) {
#pragma unroll
        for (int k = 0; k < NACC; ++k) sred[wave][k] = acc[k];
    }
    __syncthreads();

    if (threadIdx.x == 0) {
        double tot[NACC];
#pragma unroll
        for (int k = 0; k < NACC; ++k) {
            double s = 0.0;
#pragma unroll
            for (int w = 0; w < BLOCK / 64; ++w) s += sred[w][k];
            tot[k] = s;
        }

        const double dn  = (double)n;
        const double Sy  = tot[18];
        const double Syy = tot[19];
        const double vary = Syy - Sy * Sy / dn;
        double pc[6];
#pragma unroll
        for (int c = 0; c < 6; ++c) {
            const double Sx  = tot[c];
            const double Sxx = tot[6 + c];
            const double Sxy = tot[12 + c];
            const double cov  = Sxy - Sx * Sy / dn;
            const double varx = Sxx - Sx * Sx / dn;
            pc[c] = cov / (sqrt(varx) * sqrt(vary));
        }
        const double loss_old = tot[20] / dn;
        const double s = 5.0 - pc[0] - pc[1] - pc[2] - pc[3] - pc[4];
        double pen = 0.0;
#pragma unroll
        for (int c = 0; c < 5; ++c) pen += (1.0 - pc[c]) * (1.0 - pc[c]);
        pen /= s;
        const double loss = loss_old + pen + (1.0 - pc[5]);
        out[0] = (float)loss;
    }
}

extern "C" void kernel_launch(void* const* d_in, const int* in_sizes, int n_in,
                              void* d_out, int out_size, void* d_ws, size_t ws_size,
                              hipStream_t stream) {
    const float* out6 = (const float*)d_in[0];  // (n,6) f32 row-major
    const float* lab  = (const float*)d_in[1];  // (n,1) f32
    float* out = (float*)d_out;
    const int n = in_sizes[1];

    const int n2 = n & ~1;
    int ntiles = (n2 + TILE_ROWS - 1) / TILE_ROWS;
    if (ntiles < 1) ntiles = 1;

    int nblocks = MAXBLOCKS;
    const int maxb = (int)(ws_size / (PSTRIDE * sizeof(float)));
    if (nblocks > maxb)   nblocks = maxb;
    if (nblocks > ntiles) nblocks = ntiles;
    if (nblocks < 1)      nblocks = 1;

    float* part = (float*)d_ws;
    hipLaunchKernelGGL(huber_partial_kernel, dim3(nblocks), dim3(BLOCK), 0, stream,
                       out6, lab, part, n);
    hipLaunchKernelGGL(huber_final_kernel, dim3(1), dim3(BLOCK), 0, stream,
                       part, nblocks, n, out);
}

// Round 3
// 163.008 us; speedup vs baseline: 1.0836x; 1.0154x over previous
//
#include <hip/hip_runtime.h>
#include <math.h>

// Reduction layout (21 accumulators, stored padded to stride 24):
//   [0..5]   Sx[c]   = sum output[:,c]
//   [6..11]  Sxx[c]  = sum output[:,c]^2
//   [12..17] Sxy[c]  = sum output[:,c]*label
//   [18]     Sy      = sum label
//   [19]     Syy     = sum label^2
//   [20]     Hsum    = sum_rows sum_c huber*alpha
static constexpr int BLOCK     = 256;
static constexpr int NACC      = 21;
static constexpr int PSTRIDE   = 24;    // padded partial stride (float4-friendly)
static constexpr int TILE_ROWS = 1024;                // rows per LDS tile
static constexpr int TILE_F4   = TILE_ROWS * 6 / 4;   // 1536 float4 = 24 KB
static constexpr int MAXBLOCKS = 2048;

__device__ __forceinline__ void async_f4(const float4* g, float4* l) {
    // Direct global->LDS (16B per lane). LDS dest is lane-contiguous linear,
    // exactly the wave-uniform-base + lane*16 order the HW requires.
    __builtin_amdgcn_global_load_lds(
        (const __attribute__((address_space(1))) void*)g,
        (__attribute__((address_space(3))) void*)l,
        16, 0, 0);
}

__device__ __forceinline__ float fast_tanh_sq(float d) {
    // tanh(d) = 1 - 2/(exp(2d)+1); squared.
    float e = __expf(2.0f * d);
    float r = __builtin_amdgcn_rcpf(e + 1.0f);
    float t = 1.0f - 2.0f * r;
    return t * t;
}

__device__ __forceinline__ void row_accum(float acc[NACC], const float x[6], float y) {
    acc[18] += y;
    acc[19] += y * y;
    float rowh = 0.0f;
#pragma unroll
    for (int c = 0; c < 6; ++c) {
        const float xv = x[c];
        acc[c]      += xv;
        acc[6 + c]  += xv * xv;
        acc[12 + c] += xv * y;
        const float d   = xv - y;
        const float hub = 4.0f * (__builtin_amdgcn_sqrtf(1.0f + 0.25f * d * d) - 1.0f);
        const float al  = (c < 5) ? (0.2f * fast_tanh_sq(d)) : 1.0f;
        rowh += hub * al;
    }
    acc[20] += rowh;
}

__device__ __forceinline__ void chunk_accum(float acc[NACC],
                                            const float4 a, const float4 b,
                                            const float4 c, const float2 y2) {
    const float r0v[6] = {a.x, a.y, a.z, a.w, b.x, b.y};
    const float r1v[6] = {b.z, b.w, c.x, c.y, c.z, c.w};
    row_accum(acc, r0v, y2.x);
    row_accum(acc, r1v, y2.y);
}

__global__ __launch_bounds__(BLOCK) void huber_partial_kernel(
    const float* __restrict__ out6,
    const float* __restrict__ lab,
    float* __restrict__ part,
    int n)
{
    __shared__ float4 tile[TILE_F4];          // 24 KB
    __shared__ float  red[BLOCK / 64][NACC];  // cross-wave reduce

    float acc[NACC];
#pragma unroll
    for (int k = 0; k < NACC; ++k) acc[k] = 0.0f;

    const int t  = threadIdx.x;
    const int n2 = n & ~1;
    const int full_tiles = n2 / TILE_ROWS;
    const int tail_start = full_tiles * TILE_ROWS;

    const float4* gsrc = reinterpret_cast<const float4*>(out6);
    const float2* lab2 = reinterpret_cast<const float2*>(lab);

    for (int tl = blockIdx.x; tl < full_tiles; tl += gridDim.x) {
        const long long basef4 = (long long)tl * TILE_F4;

        // Global -> LDS async, 6 chunks x 256 lanes x 16B, perfectly coalesced.
#pragma unroll
        for (int k = 0; k < 6; ++k)
            async_f4(&gsrc[basef4 + k * BLOCK + t], &tile[k * BLOCK + t]);

        // Labels for this thread's 4 rows (overlap with the LDS fill).
        const float2 yA = lab2[(size_t)tl * (TILE_ROWS / 2) + t];
        const float2 yB = lab2[(size_t)tl * (TILE_ROWS / 2) + BLOCK + t];

        __syncthreads();  // drains vmcnt: LDS tile complete, labels in regs

        // Two 3-slot chunks per thread (stride-48B: odd multiplier -> every
        // bank serves exactly its structural minimum -> conflict-free).
        chunk_accum(acc, tile[3 * t + 0], tile[3 * t + 1], tile[3 * t + 2], yA);
        chunk_accum(acc, tile[TILE_F4 / 2 + 3 * t + 0],
                         tile[TILE_F4 / 2 + 3 * t + 1],
                         tile[TILE_F4 / 2 + 3 * t + 2], yB);

        __syncthreads();  // WAR: tile fully consumed before next stage
    }

    // Tail (rows tail_start..n-1, < 1025 rows): block 0, direct global loads.
    if (blockIdx.x == 0) {
        for (int r = tail_start + 2 * t; r + 1 < n2 + 1; r += 2 * BLOCK) {
            if (r + 1 >= n2) break;
            const long long g = (long long)r * 3 / 2;  // r even -> f4 index
            chunk_accum(acc, gsrc[g], gsrc[g + 1], gsrc[g + 2], lab2[r >> 1]);
        }
        if ((n & 1) && t == 0) {
            const size_t row = (size_t)n - 1;
            float xr[6];
#pragma unroll
            for (int c = 0; c < 6; ++c) xr[c] = out6[row * 6 + c];
            row_accum(acc, xr, lab[row]);
        }
    }

    // Wave (64-lane) shuffle reduction.
#pragma unroll
    for (int k = 0; k < NACC; ++k) {
        float v = acc[k];
#pragma unroll
        for (int off = 32; off > 0; off >>= 1)
            v += __shfl_down(v, off, 64);
        acc[k] = v;
    }

    const int wave = t >> 6;
    const int lane = t & 63;
    if (lane == 0) {
#pragma unroll
        for (int k = 0; k < NACC; ++k) red[wave][k] = acc[k];
    }
    __syncthreads();
    if (t < NACC) {
        float s = 0.0f;
#pragma unroll
        for (int w = 0; w < BLOCK / 64; ++w) s += red[w][t];
        part[(size_t)blockIdx.x * PSTRIDE + t] = s;
    }
}

__global__ __launch_bounds__(BLOCK) void huber_final_kernel(
    const float* __restrict__ part, int nblocks, int n, float* __restrict__ out)
{
    __shared__ double sred[BLOCK / 64][NACC];

    double acc[NACC];
#pragma unroll
    for (int k = 0; k < NACC; ++k) acc[k] = 0.0;

    for (int b = threadIdx.x; b < nblocks; b += BLOCK) {
        const float* p = part + (size_t)b * PSTRIDE;
        const float4* p4 = reinterpret_cast<const float4*>(p);
#pragma unroll
        for (int q = 0; q < 5; ++q) {
            const float4 v = p4[q];
            acc[q * 4 + 0] += (double)v.x;
            acc[q * 4 + 1] += (double)v.y;
            acc[q * 4 + 2] += (double)v.z;
            acc[q * 4 + 3] += (double)v.w;
        }
        acc[20] += (double)p[20];
    }

#pragma unroll
    for (int k = 0; k < NACC; ++k) {
        double v = acc[k];
#pragma unroll
        for (int off = 32; off > 0; off >>= 1)
            v += __shfl_down(v, off, 64);
        acc[k] = v;
    }

    const int wave = threadIdx.x >> 6;
    const int lane = threadIdx.x & 63;
    if (lane == 0) {
#pragma unroll
        for (int k = 0; k < NACC; ++k) sred[wave][k] = acc[k];
    }
    __syncthreads();

    if (threadIdx.x == 0) {
        double tot[NACC];
#pragma unroll
        for (int k = 0; k < NACC; ++k) {
            double s = 0.0;
#pragma unroll
            for (int w = 0; w < BLOCK / 64; ++w) s += sred[w][k];
            tot[k] = s;
        }

        const double dn  = (double)n;
        const double Sy  = tot[18];
        const double Syy = tot[19];
        const double vary = Syy - Sy * Sy / dn;
        double pc[6];
#pragma unroll
        for (int c = 0; c < 6; ++c) {
            const double Sx  = tot[c];
            const double Sxx = tot[6 + c];
            const double Sxy = tot[12 + c];
            const double cov  = Sxy - Sx * Sy / dn;
            const double varx = Sxx - Sx * Sx / dn;
            pc[c] = cov / (sqrt(varx) * sqrt(vary));
        }
        const double loss_old = tot[20] / dn;
        const double s = 5.0 - pc[0] - pc[1] - pc[2] - pc[3] - pc[4];
        double pen = 0.0;
#pragma unroll
        for (int c = 0; c < 5; ++c) pen += (1.0 - pc[c]) * (1.0 - pc[c]);
        pen /= s;
        const double loss = loss_old + pen + (1.0 - pc[5]);
        out[0] = (float)loss;
    }
}

extern "C" void kernel_launch(void* const* d_in, const int* in_sizes, int n_in,
                              void* d_out, int out_size, void* d_ws, size_t ws_size,
                              hipStream_t stream) {
    const float* out6 = (const float*)d_in[0];  // (n,6) f32 row-major
    const float* lab  = (const float*)d_in[1];  // (n,1) f32
    float* out = (float*)d_out;
    const int n = in_sizes[1];

    const int n2 = n & ~1;
    int full_tiles = n2 / TILE_ROWS;
    if (full_tiles < 1) full_tiles = 1;

    int nblocks = MAXBLOCKS;
    const int maxb = (int)(ws_size / (PSTRIDE * sizeof(float)));
    if (nblocks > maxb)       nblocks = maxb;
    if (nblocks > full_tiles) nblocks = full_tiles;
    if (nblocks < 1)          nblocks = 1;

    float* part = (float*)d_ws;
    hipLaunchKernelGGL(huber_partial_kernel, dim3(nblocks), dim3(BLOCK), 0, stream,
                       out6, lab, part, n);
    hipLaunchKernelGGL(huber_final_kernel, dim3(1), dim3(BLOCK), 0, stream,
                       part, nblocks, n, out);
}